// Round 16
// baseline (249.908 us; speedup 1.0000x reference)
//
#include <hip/hip_runtime.h>
#include <math.h>

// Problem constants
#define NS     16
#define T_LEN  8192
#define BATCH  8
#define CH     32

// Tiling
#define TW     248        // outputs per block (62 per wave + 2-col shfl halo)
#define BT     256
#define NTILES 34         // ceil(8192/248)
#define RS     260        // cwt row stride (dwords); cols 256..259 unused -> corr lives at col 256
#define XWELEM 800        // x window elems per copy (u = tt + k', k' < 544)
#define XCS    800        // copy stride in f16
#define NCPY   2          // shifted copies (b32 path: frag base ≡ 0 mod 2 f16)
// Two scale groups, 16x16x32 MFMA (N=16 cols = 8 scales x r/i):
//   group 1: scales 8-15, k' in [0,544), 17 K-chunks of 32
//   group 0: scales 0-7,  k' in [192,320), 4 K-chunks (taps lie in [205,308))
#define NQ0    4
#define NQ1    17
#define KOFF0  192
#define NCHUNK (NQ0 + NQ1)
#define NFRAG  (NCHUNK * 512)   // f16 per stream (10752)

typedef _Float16 f16x2 __attribute__((ext_vector_type(2)));
typedef _Float16 f16x8 __attribute__((ext_vector_type(8)));
typedef float    f32x4 __attribute__((ext_vector_type(4)));

// Per-scale constants (validated rounds 1-15)
constexpr int LT[NS]   = {13,17,23,31,41,55,75,103,139,191,259,351,477,513,513,513};
constexpr int PADT[NS] = {6,8,11,15,20,27,37,51,69,95,129,175,238,256,256,256};

// Branch-free exact-erf GELU via Abramowitz-Stegun 7.1.26 (|err_erf| <= 1.5e-7):
// erfc(|u|) ~= (a1 t + .. + a5 t^5) e^{-u^2}, t = 1/(1 + 0.3275911|u|), u = v/sqrt(2).
// gelu(v) = v - 0.5 v erfc(|u|)  (v>=0);  = 0.5 v erfc(|u|)  (v<0).
__device__ __forceinline__ float gelu_fast(float v) {
    float u  = v * 0.70710678118654752440f;
    float au = __builtin_fabsf(u);
    float t  = __builtin_amdgcn_rcpf(fmaf(0.3275911f, au, 1.0f));
    float p  = fmaf(1.061405429f, t, -1.453152027f);
    p = fmaf(p, t, 1.421413741f);
    p = fmaf(p, t, -0.284496736f);
    p = fmaf(p, t, 0.254829592f);
    p = p * t;
    float e  = exp2f(u * u * -1.4426950408889634f);   // e^{-u^2} via v_exp
    float ea = p * e;                                 // erfc(|u|)
    float gneg = 0.5f * v * ea;
    return (v < 0.0f) ? gneg : (v - gneg);
}

// Wavelet B-fragment streams (hi+lo split-f16) for 16x16x32 MFMA.
// Chunk ci (<NQ0: group0 q=ci; else group1 q=ci-NQ0). Element (ci, lane, j) at
// [ci*512 + lane*8 + j] holds B[k=8*(lane>>4)+j][n=lane&15]: tap of scale
// s = 8*grp + (n>>1) (n even=real, odd=imag) at j_tap = koff+32q+k - 256 + pad_s.
__global__ void wavelet_init(_Float16* __restrict__ whi, _Float16* __restrict__ wlo) {
    int idx0   = blockIdx.x * blockDim.x + threadIdx.x;
    int stride = gridDim.x * blockDim.x;
    for (int idx = idx0; idx < NFRAG; idx += stride) {
        int ci   = idx >> 9;
        int r    = idx & 511;
        int l    = r >> 3;
        int j    = r & 7;
        int grp  = (ci >= NQ0) ? 1 : 0;
        int q    = grp ? (ci - NQ0) : ci;
        int koff = grp ? 0 : KOFF0;
        int n    = l & 15;
        int hq   = l >> 4;
        int kp   = koff + 32 * q + 8 * hq + j;
        int s    = 8 * grp + (n >> 1);
        int ri   = n & 1;
        int L    = LT[s];
        int jt   = kp - 256 + PADT[s];
        float wf = 0.f;
        if (jt >= 0 && jt < L) {
            double e  = (s == NS - 1) ? log10(200.0)
                                      : (log10(2.0) + (double)s * ((log10(200.0) - log10(2.0)) / 15.0));
            double sc = pow(10.0, e);
            double lo = -(double)((L + 1) / 2);   // Python (-L)//2, L odd
            double hi =  (double)(L / 2);
            double st = (hi - lo) / (double)(L - 1);
            double t  = (jt == L - 1) ? hi : (lo + (double)jt * st);
            double ts = t / sc;
            double nm = 1.0 / (pow(M_PI, 0.25) * sqrt(sc));
            double g  = nm * exp(-(ts * ts) * 0.5);
            wf = (float)(ri ? (g * sin(5.0 * ts)) : (g * cos(5.0 * ts)));
        }
        _Float16 hv = (_Float16)wf;
        whi[idx] = hv;
        wlo[idx] = (_Float16)(wf - (float)hv);
    }
}

__global__ __launch_bounds__(BT, 7) void wlsc_main(
    const float* __restrict__ x,
    const float* __restrict__ w1, const float* __restrict__ b1,
    const float* __restrict__ w2, const float* __restrict__ b2,
    const float* __restrict__ blend_logit,
    const float* __restrict__ lsc,
    const _Float16* __restrict__ wfh,
    const _Float16* __restrict__ wfl,
    float* __restrict__ out)
{
    __shared__ float cwtb[NS * RS];                          // 16640 B; corr[s] at col 256
    __shared__ __align__(16) char ubuf[2 * NCPY * XCS * 2];  // 6400 B
    _Float16* xch = (_Float16*)ubuf;
    _Float16* xcl = xch + NCPY * XCS;
    // total LDS = 16640 + 6400 = 23040 B -> 7 blocks/CU

    const int tid  = threadIdx.x;
    const int tile = blockIdx.x;
    const int bc   = blockIdx.y;
    const int t0   = tile * TW;
    const int c    = bc & (CH - 1);
    const float* xbc = x + (size_t)bc * T_LEN;
    const bool interior = (t0 >= 2) && (t0 + 254 <= T_LEN);   // block-uniform

    if (tid < NS) cwtb[tid * RS + 256] = expf(lsc[tid]);      // corr in row padding

    // ---- stage x window as split-f16 into 2 shifted copies ----
    for (int v = tid; v < XWELEM + NCPY; v += BT) {
        int g = t0 - 258 + v;
        if (g < 0)      g = -g;
        if (g >= T_LEN) g = 2 * T_LEN - 2 - g;
        float xv = xbc[g];
        _Float16 hv = (_Float16)xv;
        _Float16 lv = (_Float16)(xv - (float)hv);
        #pragma unroll
        for (int cp = 0; cp < NCPY; ++cp) {
            int idx = v - cp;
            if ((unsigned)idx < XWELEM) {
                xch[cp * XCS + idx] = hv;
                xcl[cp * XCS + idx] = lv;
            }
        }
    }
    __syncthreads();

    // ---- stage 1: CWT via mfma_f32_16x16x32_f16, split-f16 3-product scheme.
    // A layout: A[m=lane&15][k=8*(lane>>4)+j]; Hankel: frag(mt+2,q)=frag(mt,q+1)
    // -> depth-2 queues for m-tile streams mt=4*wid and 4*wid+1 serve all 4. ----
    const int lane = tid & 63;
    const int wid  = tid >> 6;
    const int li   = lane & 15;
    const int hq   = lane >> 4;
    const int abase = (li & 1) * XCS + (li & ~1) + 8 * hq;
    const _Float16* pah = xch + abase;
    const _Float16* pal = xcl + abase;
    const f16x8* wh = reinterpret_cast<const f16x8*>(wfh);
    const f16x8* wl = reinterpret_cast<const f16x8*>(wfl);

#define LOADF(p, off) ({                                                      \
        const _Float16* _q = (p) + (off);                                     \
        f16x2 _a = *(const f16x2*)(_q);                                       \
        f16x2 _b = *(const f16x2*)(_q + 2);                                   \
        f16x2 _c = *(const f16x2*)(_q + 4);                                   \
        f16x2 _d = *(const f16x2*)(_q + 6);                                   \
        f16x8 _r;                                                             \
        _r[0]=_a[0]; _r[1]=_a[1]; _r[2]=_b[0]; _r[3]=_b[1];                   \
        _r[4]=_c[0]; _r[5]=_c[1]; _r[6]=_d[0]; _r[7]=_d[1];                   \
        _r; })
#define MF(A, B, C) __builtin_amdgcn_mfma_f32_16x16x32_f16((A), (B), (C), 0, 0, 0)

    const int s_even = li >> 1;          // scale within group for even-li lanes
    f32x4 ac0, ac1, ac2, ac3;

    // ---- group 1: scales 8-15, chunks 0..16 (table ci = NQ0+q), koff = 0 ----
    {
        #pragma unroll
        for (int i = 0; i < 4; ++i) { ac0[i]=0.f; ac1[i]=0.f; ac2[i]=0.f; ac3[i]=0.f; }
        const int ob = 64 * wid;
        f16x8 G0h = LOADF(pah, ob),      G0l = LOADF(pal, ob);
        f16x8 H0h = LOADF(pah, ob + 16), H0l = LOADF(pal, ob + 16);
        #pragma unroll
        for (int q = 0; q < NQ1; ++q) {
            f16x8 G1h = LOADF(pah, ob + 32 * (q + 1));
            f16x8 G1l = LOADF(pal, ob + 32 * (q + 1));
            f16x8 H1h = LOADF(pah, ob + 16 + 32 * (q + 1));
            f16x8 H1l = LOADF(pal, ob + 16 + 32 * (q + 1));
            f16x8 bh = wh[(NQ0 + q) * 64 + lane];
            f16x8 bl = wl[(NQ0 + q) * 64 + lane];
            ac0 = MF(G0h, bh, ac0); ac0 = MF(G0h, bl, ac0); ac0 = MF(G0l, bh, ac0);
            ac1 = MF(H0h, bh, ac1); ac1 = MF(H0h, bl, ac1); ac1 = MF(H0l, bh, ac1);
            ac2 = MF(G1h, bh, ac2); ac2 = MF(G1h, bl, ac2); ac2 = MF(G1l, bh, ac2);
            ac3 = MF(H1h, bh, ac3); ac3 = MF(H1h, bl, ac3); ac3 = MF(H1l, bh, ac3);
            G0h = G1h; G0l = G1l; H0h = H1h; H0l = H1l;
        }
        // epilogue: C/D row = 4*hq + e, col = li; r/i pair via shfl_xor(1)
        const int s = 8 + s_even;
        #pragma unroll
        for (int mi = 0; mi < 4; ++mi) {
            f32x4 acc = (mi == 0) ? ac0 : (mi == 1) ? ac1 : (mi == 2) ? ac2 : ac3;
            float4 mag;
            #pragma unroll
            for (int e = 0; e < 4; ++e) {
                float cr = acc[e];
                float cim = __shfl_xor(cr, 1);
                float mg = sqrtf(cr * cr + cim * cim);
                if (!interior) {
                    int ta = t0 - 2 + 16 * (4 * wid + mi) + 4 * hq + e;
                    if ((unsigned)ta >= T_LEN) mg = 0.f;
                }
                (&mag.x)[e] = mg;
            }
            if ((lane & 1) == 0)
                *reinterpret_cast<float4*>(cwtb + s * RS + 16 * (4 * wid + mi) + 4 * hq) = mag;
        }
    }

    // ---- group 0: scales 0-7, chunks 0..3 (table ci = q), koff = 192 ----
    {
        #pragma unroll
        for (int i = 0; i < 4; ++i) { ac0[i]=0.f; ac1[i]=0.f; ac2[i]=0.f; ac3[i]=0.f; }
        const int ob = 64 * wid + KOFF0;
        f16x8 G0h = LOADF(pah, ob),      G0l = LOADF(pal, ob);
        f16x8 H0h = LOADF(pah, ob + 16), H0l = LOADF(pal, ob + 16);
        #pragma unroll
        for (int q = 0; q < NQ0; ++q) {
            f16x8 G1h = LOADF(pah, ob + 32 * (q + 1));
            f16x8 G1l = LOADF(pal, ob + 32 * (q + 1));
            f16x8 H1h = LOADF(pah, ob + 16 + 32 * (q + 1));
            f16x8 H1l = LOADF(pal, ob + 16 + 32 * (q + 1));
            f16x8 bh = wh[q * 64 + lane];
            f16x8 bl = wl[q * 64 + lane];
            ac0 = MF(G0h, bh, ac0); ac0 = MF(G0h, bl, ac0); ac0 = MF(G0l, bh, ac0);
            ac1 = MF(H0h, bh, ac1); ac1 = MF(H0h, bl, ac1); ac1 = MF(H0l, bh, ac1);
            ac2 = MF(G1h, bh, ac2); ac2 = MF(G1h, bl, ac2); ac2 = MF(G1l, bh, ac2);
            ac3 = MF(H1h, bh, ac3); ac3 = MF(H1h, bl, ac3); ac3 = MF(H1l, bh, ac3);
            G0h = G1h; G0l = G1l; H0h = H1h; H0l = H1l;
        }
        const int s = s_even;
        #pragma unroll
        for (int mi = 0; mi < 4; ++mi) {
            f32x4 acc = (mi == 0) ? ac0 : (mi == 1) ? ac1 : (mi == 2) ? ac2 : ac3;
            float4 mag;
            #pragma unroll
            for (int e = 0; e < 4; ++e) {
                float cr = acc[e];
                float cim = __shfl_xor(cr, 1);
                float mg = sqrtf(cr * cr + cim * cim);
                if (!interior) {
                    int ta = t0 - 2 + 16 * (4 * wid + mi) + 4 * hq + e;
                    if ((unsigned)ta >= T_LEN) mg = 0.f;
                }
                (&mag.x)[e] = mg;
            }
            if ((lane & 1) == 0)
                *reinterpret_cast<float4*>(cwtb + s * RS + 16 * (4 * wid + mi) + 4 * hq) = mag;
        }
    }
#undef LOADF
#undef MF
    __syncthreads();

    // per-channel weights -> registers
    float W1r[9], W2r[9];
    #pragma unroll
    for (int k = 0; k < 9; ++k) { W1r[k] = w1[c * 9 + k]; W2r[k] = w2[c * 9 + k]; }
    const float B1v = b1[c], B2v = b2[c];
    const float blend = 1.f / (1.f + expf(-blend_logit[0]));

    // ---- stages 2+3 fused: h1 in registers, neighbor columns via shfl. ----
    {
        const int tt1 = 62 * wid + lane;
        const int ta  = t0 - 1 + tt1;
        const bool inb = (unsigned)ta < T_LEN;
        float h1r[NS];
        float rawcv[NS];

        // stage 2: sliding rows, 3 b32 LDS reads per row; corr at row col 256
        {
            float p0 = 0.f, p1 = 0.f, p2 = 0.f;
            float c0, c1, c2;
            {
                const float* r = cwtb + tt1;
                float cr = cwtb[256];
                float r2 = r[2];
                rawcv[0] = r2;
                c0 = r[0] * cr; c1 = r[1] * cr; c2 = r2 * cr;
            }
            #pragma unroll
            for (int s = 0; s < NS; ++s) {
                float n0 = 0.f, n1 = 0.f, n2 = 0.f;
                if (s + 1 < NS) {
                    const float* r = cwtb + (s + 1) * RS + tt1;
                    float cr = cwtb[(s + 1) * RS + 256];
                    float r2 = r[2];
                    rawcv[s + 1] = r2;
                    n0 = r[0] * cr; n1 = r[1] * cr; n2 = r2 * cr;
                }
                float acc = B1v;
                acc = fmaf(p0, W1r[0], acc); acc = fmaf(p1, W1r[1], acc); acc = fmaf(p2, W1r[2], acc);
                acc = fmaf(c0, W1r[3], acc); acc = fmaf(c1, W1r[4], acc); acc = fmaf(c2, W1r[5], acc);
                acc = fmaf(n0, W1r[6], acc); acc = fmaf(n1, W1r[7], acc); acc = fmaf(n2, W1r[8], acc);
                h1r[s] = inb ? gelu_fast(acc) : 0.f;
                p0 = c0; p1 = c1; p2 = c2;
                c0 = n0; c1 = n1; c2 = n2;
            }
        }

        // stage 3: neighbor columns via shfl_down; division via v_rcp (1 ulp)
        const int t = t0 + tt1;
        float racc = 0.f;
        float pa = 0.f, pb = 0.f, pc = 0.f;
        float ca, cb, cc;
        {
            ca = h1r[0];
            cb = __shfl_down(ca, 1);
            cc = __shfl_down(ca, 2);
        }
        #pragma unroll
        for (int s = 0; s < NS; ++s) {
            float na = 0.f, nb = 0.f, nc = 0.f;
            if (s + 1 < NS) {
                na = h1r[s + 1];
                nb = __shfl_down(na, 1);
                nc = __shfl_down(na, 2);
            }
            float acc = B2v;
            acc = fmaf(pa, W2r[0], acc); acc = fmaf(pb, W2r[1], acc); acc = fmaf(pc, W2r[2], acc);
            acc = fmaf(ca, W2r[3], acc); acc = fmaf(cb, W2r[4], acc); acc = fmaf(cc, W2r[5], acc);
            acc = fmaf(na, W2r[6], acc); acc = fmaf(nb, W2r[7], acc); acc = fmaf(nc, W2r[8], acc);
            float h2v = gelu_fast(acc);
            float cv  = rawcv[s];
            float num = blend * h2v + (1.f - blend) * cv;
            racc = fmaf(num, __builtin_amdgcn_rcpf(cv + 1e-8f), racc);
            pa = ca; pb = cb; pc = cc;
            ca = na; cb = nb; cc = nc;
        }
        if (lane < 62 && t < T_LEN)
            out[(size_t)bc * T_LEN + t] = xbc[t] * racc * (1.f / 16.f);
    }
}

extern "C" void kernel_launch(void* const* d_in, const int* in_sizes, int n_in,
                              void* d_out, int out_size, void* d_ws, size_t ws_size,
                              hipStream_t stream) {
    const float* x  = (const float*)d_in[0];
    const float* w1 = (const float*)d_in[1];
    const float* b1 = (const float*)d_in[2];
    const float* w2 = (const float*)d_in[3];
    const float* b2 = (const float*)d_in[4];
    const float* bl = (const float*)d_in[5];
    const float* ls = (const float*)d_in[6];
    float* out = (float*)d_out;

    _Float16* whi = (_Float16*)d_ws;          // NFRAG f16
    _Float16* wlo = whi + NFRAG;              // NFRAG f16

    hipLaunchKernelGGL(wavelet_init, dim3(42), dim3(256), 0, stream, whi, wlo);

    dim3 grid(NTILES, BATCH * CH);
    hipLaunchKernelGGL(wlsc_main, grid, dim3(BT), 0, stream,
                       x, w1, b1, w2, b2, bl, ls, whi, wlo, out);
}

// Round 17
// 242.079 us; speedup vs baseline: 1.0323x; 1.0323x over previous
//
#include <hip/hip_runtime.h>
#include <math.h>

// Problem constants
#define NS     16
#define T_LEN  8192
#define BATCH  8
#define CH     32

// Tiling
#define TW     248        // outputs per block (62 per wave + 2-col shfl halo)
#define BT     256
#define NTILES 34         // ceil(8192/248)
#define RS     260        // cwt row stride (dwords); corr[s] lives at col 256 (row padding)
#define XWELEM 800        // x window elems per copy (u = tt + k', k' < 544)
#define XCS    800        // copy stride in f16
#define NCPY   2          // shifted copies (b32 path: frag base ≡ 0 mod 2 f16)
// Two scale groups, 16x16x32 MFMA (N=16 cols = 8 scales x r/i):
//   group 1: scales 8-15, k' in [0,544), 17 K-chunks of 32
//   group 0: scales 0-7,  k' in [192,320), 4 K-chunks (taps lie in [205,308))
#define NQ0    4
#define NQ1    17
#define KOFF0  192
#define NCHUNK (NQ0 + NQ1)
#define NFRAG  (NCHUNK * 512)   // f16 per stream (10752)

typedef _Float16 f16x2 __attribute__((ext_vector_type(2)));
typedef _Float16 f16x8 __attribute__((ext_vector_type(8)));
typedef float    f32x4 __attribute__((ext_vector_type(4)));

// Per-scale constants (validated rounds 1-16)
constexpr int LT[NS]   = {13,17,23,31,41,55,75,103,139,191,259,351,477,513,513,513};
constexpr int PADT[NS] = {6,8,11,15,20,27,37,51,69,95,129,175,238,256,256,256};

// Branch-free exact-erf GELU via Abramowitz-Stegun 7.1.26 (|err_erf| <= 1.5e-7):
// accuracy validated round 16 (absmax 0.0156, same as libm erff path).
__device__ __forceinline__ float gelu_fast(float v) {
    float u  = v * 0.70710678118654752440f;
    float au = __builtin_fabsf(u);
    float t  = __builtin_amdgcn_rcpf(fmaf(0.3275911f, au, 1.0f));
    float p  = fmaf(1.061405429f, t, -1.453152027f);
    p = fmaf(p, t, 1.421413741f);
    p = fmaf(p, t, -0.284496736f);
    p = fmaf(p, t, 0.254829592f);
    p = p * t;
    float e  = exp2f(u * u * -1.4426950408889634f);   // e^{-u^2} via v_exp
    float ea = p * e;                                 // erfc(|u|)
    float gneg = 0.5f * v * ea;
    return (v < 0.0f) ? gneg : (v - gneg);
}

// Wavelet B-fragment streams (hi+lo split-f16) for 16x16x32 MFMA.
// Chunk ci (<NQ0: group0 q=ci; else group1 q=ci-NQ0). Element (ci, lane, j) at
// [ci*512 + lane*8 + j] holds B[k=8*(lane>>4)+j][n=lane&15]: tap of scale
// s = 8*grp + (n>>1) (n even=real, odd=imag) at j_tap = koff+32q+k - 256 + pad_s.
__global__ void wavelet_init(_Float16* __restrict__ whi, _Float16* __restrict__ wlo) {
    int idx0   = blockIdx.x * blockDim.x + threadIdx.x;
    int stride = gridDim.x * blockDim.x;
    for (int idx = idx0; idx < NFRAG; idx += stride) {
        int ci   = idx >> 9;
        int r    = idx & 511;
        int l    = r >> 3;
        int j    = r & 7;
        int grp  = (ci >= NQ0) ? 1 : 0;
        int q    = grp ? (ci - NQ0) : ci;
        int koff = grp ? 0 : KOFF0;
        int n    = l & 15;
        int hq   = l >> 4;
        int kp   = koff + 32 * q + 8 * hq + j;
        int s    = 8 * grp + (n >> 1);
        int ri   = n & 1;
        int L    = LT[s];
        int jt   = kp - 256 + PADT[s];
        float wf = 0.f;
        if (jt >= 0 && jt < L) {
            double e  = (s == NS - 1) ? log10(200.0)
                                      : (log10(2.0) + (double)s * ((log10(200.0) - log10(2.0)) / 15.0));
            double sc = pow(10.0, e);
            double lo = -(double)((L + 1) / 2);   // Python (-L)//2, L odd
            double hi =  (double)(L / 2);
            double st = (hi - lo) / (double)(L - 1);
            double t  = (jt == L - 1) ? hi : (lo + (double)jt * st);
            double ts = t / sc;
            double nm = 1.0 / (pow(M_PI, 0.25) * sqrt(sc));
            double g  = nm * exp(-(ts * ts) * 0.5);
            wf = (float)(ri ? (g * sin(5.0 * ts)) : (g * cos(5.0 * ts)));
        }
        _Float16 hv = (_Float16)wf;
        whi[idx] = hv;
        wlo[idx] = (_Float16)(wf - (float)hv);
    }
}

// launch_bounds 6 waves/EU: 7 forced 73-reg budget -> scratch spill (R16:
// FETCH 14->101 MB, WRITE 8->187 MB, dur +24us). 6 (85 regs) is spill-free max.
__global__ __launch_bounds__(BT, 6) void wlsc_main(
    const float* __restrict__ x,
    const float* __restrict__ w1, const float* __restrict__ b1,
    const float* __restrict__ w2, const float* __restrict__ b2,
    const float* __restrict__ blend_logit,
    const float* __restrict__ lsc,
    const _Float16* __restrict__ wfh,
    const _Float16* __restrict__ wfl,
    float* __restrict__ out)
{
    __shared__ float cwtb[NS * RS];                          // 16640 B; corr[s] at col 256
    __shared__ __align__(16) char ubuf[2 * NCPY * XCS * 2];  // 6400 B
    _Float16* xch = (_Float16*)ubuf;
    _Float16* xcl = xch + NCPY * XCS;
    // total LDS = 16640 + 6400 = 23040 B

    const int tid  = threadIdx.x;
    const int tile = blockIdx.x;
    const int bc   = blockIdx.y;
    const int t0   = tile * TW;
    const int c    = bc & (CH - 1);
    const float* xbc = x + (size_t)bc * T_LEN;
    const bool interior = (t0 >= 2) && (t0 + 254 <= T_LEN);   // block-uniform

    if (tid < NS) cwtb[tid * RS + 256] = expf(lsc[tid]);      // corr in row padding

    // ---- stage x window as split-f16 into 2 shifted copies ----
    for (int v = tid; v < XWELEM + NCPY; v += BT) {
        int g = t0 - 258 + v;
        if (g < 0)      g = -g;
        if (g >= T_LEN) g = 2 * T_LEN - 2 - g;
        float xv = xbc[g];
        _Float16 hv = (_Float16)xv;
        _Float16 lv = (_Float16)(xv - (float)hv);
        #pragma unroll
        for (int cp = 0; cp < NCPY; ++cp) {
            int idx = v - cp;
            if ((unsigned)idx < XWELEM) {
                xch[cp * XCS + idx] = hv;
                xcl[cp * XCS + idx] = lv;
            }
        }
    }
    __syncthreads();

    // ---- stage 1: CWT via mfma_f32_16x16x32_f16, split-f16 3-product scheme.
    // A layout: A[m=lane&15][k=8*(lane>>4)+j]; Hankel: frag(mt+2,q)=frag(mt,q+1)
    // -> depth-2 queues for m-tile streams mt=4*wid and 4*wid+1 serve all 4. ----
    const int lane = tid & 63;
    const int wid  = tid >> 6;
    const int li   = lane & 15;
    const int hq   = lane >> 4;
    const int abase = (li & 1) * XCS + (li & ~1) + 8 * hq;
    const _Float16* pah = xch + abase;
    const _Float16* pal = xcl + abase;
    const f16x8* wh = reinterpret_cast<const f16x8*>(wfh);
    const f16x8* wl = reinterpret_cast<const f16x8*>(wfl);

#define LOADF(p, off) ({                                                      \
        const _Float16* _q = (p) + (off);                                     \
        f16x2 _a = *(const f16x2*)(_q);                                       \
        f16x2 _b = *(const f16x2*)(_q + 2);                                   \
        f16x2 _c = *(const f16x2*)(_q + 4);                                   \
        f16x2 _d = *(const f16x2*)(_q + 6);                                   \
        f16x8 _r;                                                             \
        _r[0]=_a[0]; _r[1]=_a[1]; _r[2]=_b[0]; _r[3]=_b[1];                   \
        _r[4]=_c[0]; _r[5]=_c[1]; _r[6]=_d[0]; _r[7]=_d[1];                   \
        _r; })
#define MF(A, B, C) __builtin_amdgcn_mfma_f32_16x16x32_f16((A), (B), (C), 0, 0, 0)

    const int s_even = li >> 1;          // scale within group for even-li lanes
    f32x4 ac0, ac1, ac2, ac3;

    // ---- group 1: scales 8-15, chunks 0..16 (table ci = NQ0+q), koff = 0 ----
    {
        #pragma unroll
        for (int i = 0; i < 4; ++i) { ac0[i]=0.f; ac1[i]=0.f; ac2[i]=0.f; ac3[i]=0.f; }
        const int ob = 64 * wid;
        f16x8 G0h = LOADF(pah, ob),      G0l = LOADF(pal, ob);
        f16x8 H0h = LOADF(pah, ob + 16), H0l = LOADF(pal, ob + 16);
        #pragma unroll
        for (int q = 0; q < NQ1; ++q) {
            f16x8 G1h = LOADF(pah, ob + 32 * (q + 1));
            f16x8 G1l = LOADF(pal, ob + 32 * (q + 1));
            f16x8 H1h = LOADF(pah, ob + 16 + 32 * (q + 1));
            f16x8 H1l = LOADF(pal, ob + 16 + 32 * (q + 1));
            f16x8 bh = wh[(NQ0 + q) * 64 + lane];
            f16x8 bl = wl[(NQ0 + q) * 64 + lane];
            ac0 = MF(G0h, bh, ac0); ac0 = MF(G0h, bl, ac0); ac0 = MF(G0l, bh, ac0);
            ac1 = MF(H0h, bh, ac1); ac1 = MF(H0h, bl, ac1); ac1 = MF(H0l, bh, ac1);
            ac2 = MF(G1h, bh, ac2); ac2 = MF(G1h, bl, ac2); ac2 = MF(G1l, bh, ac2);
            ac3 = MF(H1h, bh, ac3); ac3 = MF(H1h, bl, ac3); ac3 = MF(H1l, bh, ac3);
            G0h = G1h; G0l = G1l; H0h = H1h; H0l = H1l;
        }
        // epilogue: C/D row = 4*hq + e, col = li; r/i pair via shfl_xor(1)
        const int s = 8 + s_even;
        #pragma unroll
        for (int mi = 0; mi < 4; ++mi) {
            f32x4 acc = (mi == 0) ? ac0 : (mi == 1) ? ac1 : (mi == 2) ? ac2 : ac3;
            float4 mag;
            #pragma unroll
            for (int e = 0; e < 4; ++e) {
                float cr = acc[e];
                float cim = __shfl_xor(cr, 1);
                float mg = sqrtf(cr * cr + cim * cim);
                if (!interior) {
                    int ta = t0 - 2 + 16 * (4 * wid + mi) + 4 * hq + e;
                    if ((unsigned)ta >= T_LEN) mg = 0.f;
                }
                (&mag.x)[e] = mg;
            }
            if ((lane & 1) == 0)
                *reinterpret_cast<float4*>(cwtb + s * RS + 16 * (4 * wid + mi) + 4 * hq) = mag;
        }
    }

    // ---- group 0: scales 0-7, chunks 0..3 (table ci = q), koff = 192 ----
    {
        #pragma unroll
        for (int i = 0; i < 4; ++i) { ac0[i]=0.f; ac1[i]=0.f; ac2[i]=0.f; ac3[i]=0.f; }
        const int ob = 64 * wid + KOFF0;
        f16x8 G0h = LOADF(pah, ob),      G0l = LOADF(pal, ob);
        f16x8 H0h = LOADF(pah, ob + 16), H0l = LOADF(pal, ob + 16);
        #pragma unroll
        for (int q = 0; q < NQ0; ++q) {
            f16x8 G1h = LOADF(pah, ob + 32 * (q + 1));
            f16x8 G1l = LOADF(pal, ob + 32 * (q + 1));
            f16x8 H1h = LOADF(pah, ob + 16 + 32 * (q + 1));
            f16x8 H1l = LOADF(pal, ob + 16 + 32 * (q + 1));
            f16x8 bh = wh[q * 64 + lane];
            f16x8 bl = wl[q * 64 + lane];
            ac0 = MF(G0h, bh, ac0); ac0 = MF(G0h, bl, ac0); ac0 = MF(G0l, bh, ac0);
            ac1 = MF(H0h, bh, ac1); ac1 = MF(H0h, bl, ac1); ac1 = MF(H0l, bh, ac1);
            ac2 = MF(G1h, bh, ac2); ac2 = MF(G1h, bl, ac2); ac2 = MF(G1l, bh, ac2);
            ac3 = MF(H1h, bh, ac3); ac3 = MF(H1h, bl, ac3); ac3 = MF(H1l, bh, ac3);
            G0h = G1h; G0l = G1l; H0h = H1h; H0l = H1l;
        }
        const int s = s_even;
        #pragma unroll
        for (int mi = 0; mi < 4; ++mi) {
            f32x4 acc = (mi == 0) ? ac0 : (mi == 1) ? ac1 : (mi == 2) ? ac2 : ac3;
            float4 mag;
            #pragma unroll
            for (int e = 0; e < 4; ++e) {
                float cr = acc[e];
                float cim = __shfl_xor(cr, 1);
                float mg = sqrtf(cr * cr + cim * cim);
                if (!interior) {
                    int ta = t0 - 2 + 16 * (4 * wid + mi) + 4 * hq + e;
                    if ((unsigned)ta >= T_LEN) mg = 0.f;
                }
                (&mag.x)[e] = mg;
            }
            if ((lane & 1) == 0)
                *reinterpret_cast<float4*>(cwtb + s * RS + 16 * (4 * wid + mi) + 4 * hq) = mag;
        }
    }
#undef LOADF
#undef MF
    __syncthreads();

    // per-channel weights -> registers
    float W1r[9], W2r[9];
    #pragma unroll
    for (int k = 0; k < 9; ++k) { W1r[k] = w1[c * 9 + k]; W2r[k] = w2[c * 9 + k]; }
    const float B1v = b1[c], B2v = b2[c];
    const float blend = 1.f / (1.f + expf(-blend_logit[0]));

    // ---- stages 2+3 fused: h1 in registers, neighbor columns via shfl. ----
    {
        const int tt1 = 62 * wid + lane;
        const int ta  = t0 - 1 + tt1;
        const bool inb = (unsigned)ta < T_LEN;
        float h1r[NS];
        float rawcv[NS];

        // stage 2: sliding rows, 3 b32 LDS reads per row; corr at row col 256
        {
            float p0 = 0.f, p1 = 0.f, p2 = 0.f;
            float c0, c1, c2;
            {
                const float* r = cwtb + tt1;
                float cr = cwtb[256];
                float r2 = r[2];
                rawcv[0] = r2;
                c0 = r[0] * cr; c1 = r[1] * cr; c2 = r2 * cr;
            }
            #pragma unroll
            for (int s = 0; s < NS; ++s) {
                float n0 = 0.f, n1 = 0.f, n2 = 0.f;
                if (s + 1 < NS) {
                    const float* r = cwtb + (s + 1) * RS + tt1;
                    float cr = cwtb[(s + 1) * RS + 256];
                    float r2 = r[2];
                    rawcv[s + 1] = r2;
                    n0 = r[0] * cr; n1 = r[1] * cr; n2 = r2 * cr;
                }
                float acc = B1v;
                acc = fmaf(p0, W1r[0], acc); acc = fmaf(p1, W1r[1], acc); acc = fmaf(p2, W1r[2], acc);
                acc = fmaf(c0, W1r[3], acc); acc = fmaf(c1, W1r[4], acc); acc = fmaf(c2, W1r[5], acc);
                acc = fmaf(n0, W1r[6], acc); acc = fmaf(n1, W1r[7], acc); acc = fmaf(n2, W1r[8], acc);
                h1r[s] = inb ? gelu_fast(acc) : 0.f;
                p0 = c0; p1 = c1; p2 = c2;
                c0 = n0; c1 = n1; c2 = n2;
            }
        }

        // stage 3: neighbor columns via shfl_down; division via v_rcp (1 ulp)
        const int t = t0 + tt1;
        float racc = 0.f;
        float pa = 0.f, pb = 0.f, pc = 0.f;
        float ca, cb, cc;
        {
            ca = h1r[0];
            cb = __shfl_down(ca, 1);
            cc = __shfl_down(ca, 2);
        }
        #pragma unroll
        for (int s = 0; s < NS; ++s) {
            float na = 0.f, nb = 0.f, nc = 0.f;
            if (s + 1 < NS) {
                na = h1r[s + 1];
                nb = __shfl_down(na, 1);
                nc = __shfl_down(na, 2);
            }
            float acc = B2v;
            acc = fmaf(pa, W2r[0], acc); acc = fmaf(pb, W2r[1], acc); acc = fmaf(pc, W2r[2], acc);
            acc = fmaf(ca, W2r[3], acc); acc = fmaf(cb, W2r[4], acc); acc = fmaf(cc, W2r[5], acc);
            acc = fmaf(na, W2r[6], acc); acc = fmaf(nb, W2r[7], acc); acc = fmaf(nc, W2r[8], acc);
            float h2v = gelu_fast(acc);
            float cv  = rawcv[s];
            float num = blend * h2v + (1.f - blend) * cv;
            racc = fmaf(num, __builtin_amdgcn_rcpf(cv + 1e-8f), racc);
            pa = ca; pb = cb; pc = cc;
            ca = na; cb = nb; cc = nc;
        }
        if (lane < 62 && t < T_LEN)
            out[(size_t)bc * T_LEN + t] = xbc[t] * racc * (1.f / 16.f);
    }
}

extern "C" void kernel_launch(void* const* d_in, const int* in_sizes, int n_in,
                              void* d_out, int out_size, void* d_ws, size_t ws_size,
                              hipStream_t stream) {
    const float* x  = (const float*)d_in[0];
    const float* w1 = (const float*)d_in[1];
    const float* b1 = (const float*)d_in[2];
    const float* w2 = (const float*)d_in[3];
    const float* b2 = (const float*)d_in[4];
    const float* bl = (const float*)d_in[5];
    const float* ls = (const float*)d_in[6];
    float* out = (float*)d_out;

    _Float16* whi = (_Float16*)d_ws;          // NFRAG f16
    _Float16* wlo = whi + NFRAG;              // NFRAG f16

    hipLaunchKernelGGL(wavelet_init, dim3(42), dim3(256), 0, stream, whi, wlo);

    dim3 grid(NTILES, BATCH * CH);
    hipLaunchKernelGGL(wlsc_main, grid, dim3(BT), 0, stream,
                       x, w1, b1, w2, b2, bl, ls, whi, wlo, out);
}

// Round 18
// 234.750 us; speedup vs baseline: 1.0646x; 1.0312x over previous
//
#include <hip/hip_runtime.h>
#include <math.h>

// Problem constants
#define NS     16
#define T_LEN  8192
#define BATCH  8
#define CH     32

// Tiling
#define TW     248        // outputs per block (62 per wave + 2-col shfl halo)
#define BT     256
#define NTILES 34         // ceil(8192/248)
#define RS     260        // cwt row stride (dwords)
#define XWELEM 800        // x window elems per copy (u = tt + k', k' < 544)
#define XCS    800        // copy stride in f16
#define NCPY   2          // shifted copies (b32 path: frag base ≡ 0 mod 2 f16)
// Two scale groups, 16x16x32 MFMA (N=16 cols = 8 scales x r/i):
//   group 1: scales 8-15, k' in [0,544), 17 K-chunks of 32
//   group 0: scales 0-7,  k' in [192,320), 4 K-chunks (taps lie in [205,308))
#define NQ0    4
#define NQ1    17
#define KOFF0  192
#define NCHUNK (NQ0 + NQ1)
#define NFRAG  (NCHUNK * 512)   // f16 per stream (10752)

typedef _Float16 f16x2 __attribute__((ext_vector_type(2)));
typedef _Float16 f16x8 __attribute__((ext_vector_type(8)));
typedef float    f32x4 __attribute__((ext_vector_type(4)));

// Per-scale constants (validated rounds 1-17)
constexpr int LT[NS]   = {13,17,23,31,41,55,75,103,139,191,259,351,477,513,513,513};
constexpr int PADT[NS] = {6,8,11,15,20,27,37,51,69,95,129,175,238,256,256,256};

// Branch-free exact-erf GELU via A&S 7.1.26 (|err_erf| <= 1.5e-7).
// Accuracy validated rounds 16-17 (absmax 0.0156, same as libm erff path).
__device__ __forceinline__ float gelu_fast(float v) {
    float u  = v * 0.70710678118654752440f;
    float au = __builtin_fabsf(u);
    float t  = __builtin_amdgcn_rcpf(fmaf(0.3275911f, au, 1.0f));
    float p  = fmaf(1.061405429f, t, -1.453152027f);
    p = fmaf(p, t, 1.421413741f);
    p = fmaf(p, t, -0.284496736f);
    p = fmaf(p, t, 0.254829592f);
    p = p * t;
    float e  = exp2f(u * u * -1.4426950408889634f);   // e^{-u^2} via v_exp
    float gneg = 0.5f * v * (p * e);                  // 0.5 v erfc(|u|)
    return (v < 0.0f) ? gneg : (v - gneg);
}

// Wavelet B-fragment streams (hi+lo split-f16) for 16x16x32 MFMA.
// Chunk ci (<NQ0: group0 q=ci; else group1 q=ci-NQ0). Element (ci, lane, j) at
// [ci*512 + lane*8 + j] holds B[k=8*(lane>>4)+j][n=lane&15]: tap of scale
// s = 8*grp + (n>>1) (n even=real, odd=imag) at j_tap = koff+32q+k - 256 + pad_s.
__global__ void wavelet_init(_Float16* __restrict__ whi, _Float16* __restrict__ wlo) {
    int idx0   = blockIdx.x * blockDim.x + threadIdx.x;
    int stride = gridDim.x * blockDim.x;
    for (int idx = idx0; idx < NFRAG; idx += stride) {
        int ci   = idx >> 9;
        int r    = idx & 511;
        int l    = r >> 3;
        int j    = r & 7;
        int grp  = (ci >= NQ0) ? 1 : 0;
        int q    = grp ? (ci - NQ0) : ci;
        int koff = grp ? 0 : KOFF0;
        int n    = l & 15;
        int hq   = l >> 4;
        int kp   = koff + 32 * q + 8 * hq + j;
        int s    = 8 * grp + (n >> 1);
        int ri   = n & 1;
        int L    = LT[s];
        int jt   = kp - 256 + PADT[s];
        float wf = 0.f;
        if (jt >= 0 && jt < L) {
            double e  = (s == NS - 1) ? log10(200.0)
                                      : (log10(2.0) + (double)s * ((log10(200.0) - log10(2.0)) / 15.0));
            double sc = pow(10.0, e);
            double lo = -(double)((L + 1) / 2);   // Python (-L)//2, L odd
            double hi =  (double)(L / 2);
            double st = (hi - lo) / (double)(L - 1);
            double t  = (jt == L - 1) ? hi : (lo + (double)jt * st);
            double ts = t / sc;
            double nm = 1.0 / (pow(M_PI, 0.25) * sqrt(sc));
            double g  = nm * exp(-(ts * ts) * 0.5);
            wf = (float)(ri ? (g * sin(5.0 * ts)) : (g * cos(5.0 * ts)));
        }
        _Float16 hv = (_Float16)wf;
        whi[idx] = hv;
        wlo[idx] = (_Float16)(wf - (float)hv);
    }
}

__global__ __launch_bounds__(BT, 6) void wlsc_main(
    const float* __restrict__ x,
    const float* __restrict__ w1, const float* __restrict__ b1,
    const float* __restrict__ w2, const float* __restrict__ b2,
    const float* __restrict__ blend_logit,
    const float* __restrict__ lsc,
    const _Float16* __restrict__ wfh,
    const _Float16* __restrict__ wfl,
    float* __restrict__ out)
{
    __shared__ float cwtb[NS * RS];                          // 16640 B
    __shared__ __align__(16) char ubuf[2 * NCPY * XCS * 2];  // 6400 B
    __shared__ float corr[NS];
    _Float16* xch = (_Float16*)ubuf;
    _Float16* xcl = xch + NCPY * XCS;
    // total LDS = 16640 + 6400 + 64 = 23104 B

    const int tid  = threadIdx.x;
    const int tile = blockIdx.x;
    const int bc   = blockIdx.y;
    const int t0   = tile * TW;
    const int c    = bc & (CH - 1);
    const float* xbc = x + (size_t)bc * T_LEN;
    const bool interior = (t0 >= 2) && (t0 + 254 <= T_LEN);   // block-uniform

    if (tid < NS) corr[tid] = expf(lsc[tid]);

    // ---- stage x window as split-f16 into 2 shifted copies ----
    for (int v = tid; v < XWELEM + NCPY; v += BT) {
        int g = t0 - 258 + v;
        if (g < 0)      g = -g;
        if (g >= T_LEN) g = 2 * T_LEN - 2 - g;
        float xv = xbc[g];
        _Float16 hv = (_Float16)xv;
        _Float16 lv = (_Float16)(xv - (float)hv);
        #pragma unroll
        for (int cp = 0; cp < NCPY; ++cp) {
            int idx = v - cp;
            if ((unsigned)idx < XWELEM) {
                xch[cp * XCS + idx] = hv;
                xcl[cp * XCS + idx] = lv;
            }
        }
    }
    __syncthreads();

    // ---- stage 1: CWT via mfma_f32_16x16x32_f16, split-f16 3-product scheme.
    // A layout: A[m=lane&15][k=8*(lane>>4)+j]; Hankel: frag(mt+2,q)=frag(mt,q+1)
    // -> depth-2 queues for m-tile streams mt=4*wid and 4*wid+1 serve all 4. ----
    const int lane = tid & 63;
    const int wid  = tid >> 6;
    const int li   = lane & 15;
    const int hq   = lane >> 4;
    const int abase = (li & 1) * XCS + (li & ~1) + 8 * hq;
    const _Float16* pah = xch + abase;
    const _Float16* pal = xcl + abase;
    const f16x8* wh = reinterpret_cast<const f16x8*>(wfh);
    const f16x8* wl = reinterpret_cast<const f16x8*>(wfl);

#define LOADF(p, off) ({                                                      \
        const _Float16* _q = (p) + (off);                                     \
        f16x2 _a = *(const f16x2*)(_q);                                       \
        f16x2 _b = *(const f16x2*)(_q + 2);                                   \
        f16x2 _c = *(const f16x2*)(_q + 4);                                   \
        f16x2 _d = *(const f16x2*)(_q + 6);                                   \
        f16x8 _r;                                                             \
        _r[0]=_a[0]; _r[1]=_a[1]; _r[2]=_b[0]; _r[3]=_b[1];                   \
        _r[4]=_c[0]; _r[5]=_c[1]; _r[6]=_d[0]; _r[7]=_d[1];                   \
        _r; })
#define MF(A, B, C) __builtin_amdgcn_mfma_f32_16x16x32_f16((A), (B), (C), 0, 0, 0)

    const int s_even = li >> 1;          // scale within group for even-li lanes
    f32x4 ac0, ac1, ac2, ac3;

    // ---- group 1: scales 8-15, chunks 0..16 (table ci = NQ0+q), koff = 0 ----
    {
        #pragma unroll
        for (int i = 0; i < 4; ++i) { ac0[i]=0.f; ac1[i]=0.f; ac2[i]=0.f; ac3[i]=0.f; }
        const int ob = 64 * wid;
        f16x8 G0h = LOADF(pah, ob),      G0l = LOADF(pal, ob);
        f16x8 H0h = LOADF(pah, ob + 16), H0l = LOADF(pal, ob + 16);
        #pragma unroll
        for (int q = 0; q < NQ1; ++q) {
            f16x8 G1h = LOADF(pah, ob + 32 * (q + 1));
            f16x8 G1l = LOADF(pal, ob + 32 * (q + 1));
            f16x8 H1h = LOADF(pah, ob + 16 + 32 * (q + 1));
            f16x8 H1l = LOADF(pal, ob + 16 + 32 * (q + 1));
            f16x8 bh = wh[(NQ0 + q) * 64 + lane];
            f16x8 bl = wl[(NQ0 + q) * 64 + lane];
            ac0 = MF(G0h, bh, ac0); ac0 = MF(G0h, bl, ac0); ac0 = MF(G0l, bh, ac0);
            ac1 = MF(H0h, bh, ac1); ac1 = MF(H0h, bl, ac1); ac1 = MF(H0l, bh, ac1);
            ac2 = MF(G1h, bh, ac2); ac2 = MF(G1h, bl, ac2); ac2 = MF(G1l, bh, ac2);
            ac3 = MF(H1h, bh, ac3); ac3 = MF(H1h, bl, ac3); ac3 = MF(H1l, bh, ac3);
            G0h = G1h; G0l = G1l; H0h = H1h; H0l = H1l;
        }
        // epilogue: C/D row = 4*hq + e, col = li; r/i pair via shfl_xor(1)
        const int s = 8 + s_even;
        #pragma unroll
        for (int mi = 0; mi < 4; ++mi) {
            f32x4 acc = (mi == 0) ? ac0 : (mi == 1) ? ac1 : (mi == 2) ? ac2 : ac3;
            float4 mag;
            #pragma unroll
            for (int e = 0; e < 4; ++e) {
                float cr = acc[e];
                float cim = __shfl_xor(cr, 1);
                float mg = sqrtf(cr * cr + cim * cim);
                if (!interior) {
                    int ta = t0 - 2 + 16 * (4 * wid + mi) + 4 * hq + e;
                    if ((unsigned)ta >= T_LEN) mg = 0.f;
                }
                (&mag.x)[e] = mg;
            }
            if ((lane & 1) == 0)
                *reinterpret_cast<float4*>(cwtb + s * RS + 16 * (4 * wid + mi) + 4 * hq) = mag;
        }
    }

    // ---- group 0: scales 0-7, chunks 0..3 (table ci = q), koff = 192 ----
    {
        #pragma unroll
        for (int i = 0; i < 4; ++i) { ac0[i]=0.f; ac1[i]=0.f; ac2[i]=0.f; ac3[i]=0.f; }
        const int ob = 64 * wid + KOFF0;
        f16x8 G0h = LOADF(pah, ob),      G0l = LOADF(pal, ob);
        f16x8 H0h = LOADF(pah, ob + 16), H0l = LOADF(pal, ob + 16);
        #pragma unroll
        for (int q = 0; q < NQ0; ++q) {
            f16x8 G1h = LOADF(pah, ob + 32 * (q + 1));
            f16x8 G1l = LOADF(pal, ob + 32 * (q + 1));
            f16x8 H1h = LOADF(pah, ob + 16 + 32 * (q + 1));
            f16x8 H1l = LOADF(pal, ob + 16 + 32 * (q + 1));
            f16x8 bh = wh[q * 64 + lane];
            f16x8 bl = wl[q * 64 + lane];
            ac0 = MF(G0h, bh, ac0); ac0 = MF(G0h, bl, ac0); ac0 = MF(G0l, bh, ac0);
            ac1 = MF(H0h, bh, ac1); ac1 = MF(H0h, bl, ac1); ac1 = MF(H0l, bh, ac1);
            ac2 = MF(G1h, bh, ac2); ac2 = MF(G1h, bl, ac2); ac2 = MF(G1l, bh, ac2);
            ac3 = MF(H1h, bh, ac3); ac3 = MF(H1h, bl, ac3); ac3 = MF(H1l, bh, ac3);
            G0h = G1h; G0l = G1l; H0h = H1h; H0l = H1l;
        }
        const int s = s_even;
        #pragma unroll
        for (int mi = 0; mi < 4; ++mi) {
            f32x4 acc = (mi == 0) ? ac0 : (mi == 1) ? ac1 : (mi == 2) ? ac2 : ac3;
            float4 mag;
            #pragma unroll
            for (int e = 0; e < 4; ++e) {
                float cr = acc[e];
                float cim = __shfl_xor(cr, 1);
                float mg = sqrtf(cr * cr + cim * cim);
                if (!interior) {
                    int ta = t0 - 2 + 16 * (4 * wid + mi) + 4 * hq + e;
                    if ((unsigned)ta >= T_LEN) mg = 0.f;
                }
                (&mag.x)[e] = mg;
            }
            if ((lane & 1) == 0)
                *reinterpret_cast<float4*>(cwtb + s * RS + 16 * (4 * wid + mi) + 4 * hq) = mag;
        }
    }
#undef LOADF
#undef MF
    __syncthreads();

    // per-channel weights -> registers
    float W1r[9], W2r[9];
    #pragma unroll
    for (int k = 0; k < 9; ++k) { W1r[k] = w1[c * 9 + k]; W2r[k] = w2[c * 9 + k]; }
    const float B1v = b1[c], B2v = b2[c];
    const float blend = 1.f / (1.f + expf(-blend_logit[0]));

    // ---- stages 2+3 fused with s-sliding state (NO 16-elem register arrays:
    // R16/R17 showed full h1r[16]/rawcv[16] + inline gelu => scratch spill,
    // WRITE_SIZE 8->75/187 MB). Live state: 2 scaled cwt rows + fresh, 3 h1
    // rows (3 cols each via cached shfl), 2-deep raw-cv chain. ----
    {
        const int tt1 = 62 * wid + lane;              // h1 column; output col for lane<62
        const bool inb = (unsigned)(t0 - 1 + tt1) < T_LEN;
        const int t = t0 + tt1;

        float A0, A1, A2, B0, B1, B2, cvA, cvB;       // scaled rows s, s+1; raw col+2
        {
            const float* r = cwtb + tt1;
            float cr = corr[0];
            cvA = r[2];
            A0 = r[0] * cr; A1 = r[1] * cr; A2 = cvA * cr;
        }
        {
            const float* r = cwtb + RS + tt1;
            float cr = corr[1];
            cvB = r[2];
            B0 = r[0] * cr; B1 = r[1] * cr; B2 = cvB * cr;
        }
        // h1 row -1 = 0; h1 row 0 from rows (-1)=0, 0, 1:
        float h1pa = 0.f, h1pb = 0.f, h1pc = 0.f;
        float h1ca, h1cb, h1cc;
        {
            float acc = B1v;
            acc = fmaf(A0, W1r[3], acc); acc = fmaf(A1, W1r[4], acc); acc = fmaf(A2, W1r[5], acc);
            acc = fmaf(B0, W1r[6], acc); acc = fmaf(B1, W1r[7], acc); acc = fmaf(B2, W1r[8], acc);
            h1ca = inb ? gelu_fast(acc) : 0.f;
            h1cb = __shfl_down(h1ca, 1);
            h1cc = __shfl_down(h1ca, 2);
        }
        float racc = 0.f;
        #pragma unroll
        for (int s = 0; s < NS; ++s) {
            // fresh scaled row s+2 (zeros past the last scale)
            float C0 = 0.f, C1 = 0.f, C2 = 0.f, cvC = 0.f;
            if (s + 2 < NS) {
                const float* r = cwtb + (s + 2) * RS + tt1;
                float cr = corr[s + 2];
                cvC = r[2];
                C0 = r[0] * cr; C1 = r[1] * cr; C2 = cvC * cr;
            }
            // h1 row s+1 from rows s, s+1, s+2 (= A, B, C)
            float h1na = 0.f;
            if (s + 1 < NS) {
                float acc = B1v;
                acc = fmaf(A0, W1r[0], acc); acc = fmaf(A1, W1r[1], acc); acc = fmaf(A2, W1r[2], acc);
                acc = fmaf(B0, W1r[3], acc); acc = fmaf(B1, W1r[4], acc); acc = fmaf(B2, W1r[5], acc);
                acc = fmaf(C0, W1r[6], acc); acc = fmaf(C1, W1r[7], acc); acc = fmaf(C2, W1r[8], acc);
                h1na = inb ? gelu_fast(acc) : 0.f;
            }
            float h1nb = __shfl_down(h1na, 1);
            float h1nc = __shfl_down(h1na, 2);
            // h2 for scale s from h1 rows s-1, s, s+1
            float acc = B2v;
            acc = fmaf(h1pa, W2r[0], acc); acc = fmaf(h1pb, W2r[1], acc); acc = fmaf(h1pc, W2r[2], acc);
            acc = fmaf(h1ca, W2r[3], acc); acc = fmaf(h1cb, W2r[4], acc); acc = fmaf(h1cc, W2r[5], acc);
            acc = fmaf(h1na, W2r[6], acc); acc = fmaf(h1nb, W2r[7], acc); acc = fmaf(h1nc, W2r[8], acc);
            float h2v = gelu_fast(acc);
            float num = blend * h2v + (1.f - blend) * cvA;   // cvA = raw cwt[s][tt1+2]
            racc = fmaf(num, __builtin_amdgcn_rcpf(cvA + 1e-8f), racc);
            // rotate sliding state
            A0 = B0; A1 = B1; A2 = B2;  B0 = C0; B1 = C1; B2 = C2;
            cvA = cvB; cvB = cvC;
            h1pa = h1ca; h1pb = h1cb; h1pc = h1cc;
            h1ca = h1na; h1cb = h1nb; h1cc = h1nc;
        }
        if (lane < 62 && t < T_LEN)
            out[(size_t)bc * T_LEN + t] = xbc[t] * racc * (1.f / 16.f);
    }
}

extern "C" void kernel_launch(void* const* d_in, const int* in_sizes, int n_in,
                              void* d_out, int out_size, void* d_ws, size_t ws_size,
                              hipStream_t stream) {
    const float* x  = (const float*)d_in[0];
    const float* w1 = (const float*)d_in[1];
    const float* b1 = (const float*)d_in[2];
    const float* w2 = (const float*)d_in[3];
    const float* b2 = (const float*)d_in[4];
    const float* bl = (const float*)d_in[5];
    const float* ls = (const float*)d_in[6];
    float* out = (float*)d_out;

    _Float16* whi = (_Float16*)d_ws;          // NFRAG f16
    _Float16* wlo = whi + NFRAG;              // NFRAG f16

    hipLaunchKernelGGL(wavelet_init, dim3(42), dim3(256), 0, stream, whi, wlo);

    dim3 grid(NTILES, BATCH * CH);
    hipLaunchKernelGGL(wlsc_main, grid, dim3(BT), 0, stream,
                       x, w1, b1, w2, b2, bl, ls, whi, wlo, out);
}